// Round 3
// baseline (184.930 us; speedup 1.0000x reference)
//
#include <hip/hip_runtime.h>

// Problem constants (from reference):
//   x:       [B=16, E=64, S=32768] float32
//   indices: [B=16, E=64] int (values in [0, S/STEP))
//   out:     [B, 1, S] float32  -> flat B*S
// out[b,s] = sum_e x[b, e, s - idx[b,e]*STEP]  where idx*STEP <= s
constexpr int B = 16;
constexpr int E = 64;
constexpr int S = 32768;
constexpr int STEP = 256;
constexpr int SAMPLES_PER_BLOCK = 1024;   // 256 threads * float4
constexpr int ESPLIT = 8;                 // event-dim split across blocks
constexpr int EPB = E / ESPLIT;           // 8 events per block

// Kernel 1: each block sums its 8 events' contribution for 1024 samples,
// writes a partial row to ws. Grid (32, 16, 8) = 4096 blocks -> 32 waves/CU
// resident (vs 8 before): 4x the CU-level memory-level parallelism.
__global__ __launch_bounds__(256)
void gather_partial(const float* __restrict__ x,
                    const int* __restrict__ idx,
                    float* __restrict__ part) {
    const int b  = blockIdx.y;
    const int ez = blockIdx.z;
    const int s0 = blockIdx.x * SAMPLES_PER_BLOCK + threadIdx.x * 4;

    __shared__ int t_lds[EPB];
    if (threadIdx.x < EPB) {
        t_lds[threadIdx.x] = idx[b * E + ez * EPB + threadIdx.x] * STEP;
    }
    __syncthreads();

    const float* xb = x + ((size_t)b * E + (size_t)ez * EPB) * S;

    // Unconditional clamped loads (address always in-range), masked after.
    // All 8 issue back-to-back -> 8 outstanding loads per thread.
    float4 v[EPB];
    float  m[EPB];
    #pragma unroll
    for (int j = 0; j < EPB; ++j) {
        const int off  = s0 - t_lds[j];
        const int offc = off < 0 ? 0 : off;
        m[j] = off < 0 ? 0.0f : 1.0f;
        v[j] = *reinterpret_cast<const float4*>(xb + (size_t)j * S + offc);
    }

    float4 acc = make_float4(0.f, 0.f, 0.f, 0.f);
    #pragma unroll
    for (int j = 0; j < EPB; ++j) {
        acc.x += m[j] * v[j].x;
        acc.y += m[j] * v[j].y;
        acc.z += m[j] * v[j].z;
        acc.w += m[j] * v[j].w;
    }

    // partial layout: [ESPLIT][B][S]
    *reinterpret_cast<float4*>(part + ((size_t)ez * B + b) * S + s0) = acc;
}

// Kernel 2: reduce the 8 partial buffers into out. 16 MB read + 2 MB write.
__global__ __launch_bounds__(256)
void reduce_partials(const float* __restrict__ part,
                     float* __restrict__ out) {
    const size_t i = ((size_t)blockIdx.x * 256 + threadIdx.x) * 4;  // over B*S

    float4 v[ESPLIT];
    #pragma unroll
    for (int p = 0; p < ESPLIT; ++p) {
        v[p] = *reinterpret_cast<const float4*>(part + (size_t)p * B * S + i);
    }
    float4 acc = make_float4(0.f, 0.f, 0.f, 0.f);
    #pragma unroll
    for (int p = 0; p < ESPLIT; ++p) {
        acc.x += v[p].x;
        acc.y += v[p].y;
        acc.z += v[p].z;
        acc.w += v[p].w;
    }
    *reinterpret_cast<float4*>(out + i) = acc;
}

extern "C" void kernel_launch(void* const* d_in, const int* in_sizes, int n_in,
                              void* d_out, int out_size, void* d_ws, size_t ws_size,
                              hipStream_t stream) {
    const float* x    = (const float*)d_in[0];
    const int*   idx  = (const int*)d_in[1];
    float*       out  = (float*)d_out;
    float*       part = (float*)d_ws;  // needs ESPLIT*B*S*4 = 16 MB

    dim3 grid1(S / SAMPLES_PER_BLOCK, B, ESPLIT);  // (32, 16, 8)
    gather_partial<<<grid1, dim3(256), 0, stream>>>(x, idx, part);

    const int total = B * S;                        // 524288 elements
    dim3 grid2(total / (256 * 4));                  // 512 blocks
    reduce_partials<<<grid2, dim3(256), 0, stream>>>(part, out);
}

// Round 5
// 175.614 us; speedup vs baseline: 1.0530x; 1.0530x over previous
//
#include <hip/hip_runtime.h>

// Problem constants (from reference):
//   x:       [B=16, E=64, S=32768] float32
//   indices: [B=16, E=64] int (values in [0, S/STEP))
//   out:     [B, 1, S] float32  -> flat B*S
// out[b,s] = sum_e x[b, e, s - idx[b,e]*STEP]  where idx*STEP <= s
constexpr int B = 16;
constexpr int E = 64;
constexpr int S = 32768;
constexpr int STEP = 256;
constexpr int HALF = 512;      // samples per half-tile
constexpr int GRP  = 16;       // loads in flight per thread

// Load-balanced gather: per-tile HBM demand is proportional to how many
// events have te <= s0 (ranges ~0 for tile 0 to 64 for the last tile).
// Pairing half-tile pr with half-tile 63-pr inside one block makes every
// block's demand ~constant (~64.5 KB) regardless of CU assignment.
// Waves 0-1 (threads 0..127) cover half-tile pr; waves 2-3 cover 63-pr.
// Tiles {pr} U {63-pr} over pr in [0,32) partition all 64 half-tiles.
__global__ __launch_bounds__(256)
void sparse_audio_gather(const float* __restrict__ x,
                         const int* __restrict__ idx,
                         float* __restrict__ out) {
    const int b     = blockIdx.y;
    const int pr    = blockIdx.x;                       // 0..31
    const int lo    = (threadIdx.x < 128);              // wave-uniform
    const int half  = lo ? pr : (63 - pr);
    const int local = (int)(threadIdx.x & 127);
    const int s0    = half * HALF + local * 4;          // < S always

    // Stage the 64 per-batch event offsets (block-uniform) in LDS.
    __shared__ int t_lds[E];
    if (threadIdx.x < E) {
        t_lds[threadIdx.x] = idx[b * E + (int)threadIdx.x] * STEP;
    }
    __syncthreads();

    const float* xb = x + (size_t)b * E * S;

    float4 acc = make_float4(0.f, 0.f, 0.f, 0.f);

    // Unconditional clamped loads (address max(s0-te,0) is always in
    // [0, s0] subset [0, S-4]), masked after the fact: GRP loads issue
    // back-to-back before any s_waitcnt -> 16 outstanding per thread.
    for (int e0 = 0; e0 < E; e0 += GRP) {
        float4 v[GRP];
        float  m[GRP];
        #pragma unroll
        for (int j = 0; j < GRP; ++j) {
            const int off  = s0 - t_lds[e0 + j];
            const int offc = off < 0 ? 0 : off;
            m[j] = off < 0 ? 0.0f : 1.0f;
            v[j] = *reinterpret_cast<const float4*>(
                       xb + (size_t)(e0 + j) * S + offc);
        }
        #pragma unroll
        for (int j = 0; j < GRP; ++j) {
            acc.x += m[j] * v[j].x;
            acc.y += m[j] * v[j].y;
            acc.z += m[j] * v[j].z;
            acc.w += m[j] * v[j].w;
        }
    }

    *reinterpret_cast<float4*>(out + (size_t)b * S + s0) = acc;
}

extern "C" void kernel_launch(void* const* d_in, const int* in_sizes, int n_in,
                              void* d_out, int out_size, void* d_ws, size_t ws_size,
                              hipStream_t stream) {
    const float* x   = (const float*)d_in[0];
    const int*   idx = (const int*)d_in[1];
    float*       out = (float*)d_out;

    dim3 grid(S / (2 * HALF), B);   // (32, 16) — each block does 2 half-tiles
    dim3 block(256);
    sparse_audio_gather<<<grid, block, 0, stream>>>(x, idx, out);
}